// Round 18
// baseline (24426.151 us; speedup 1.0000x reference)
//
#include <hip/hip_runtime.h>
#include <math.h>

#define BS   4
#define QLEN 2048
#define DIM  1024
#define NH   16
#define DH   64

// =====================================================================
// Kernel 1: fused QKV projection GEMM (gridDim.z selects Q/K/V).
//   UNCHANGED from round 17.
// =====================================================================
#define GBM 64
#define GBN 64
#define GBK 32
#define GST (GBK + 4)    // 36 floats: 144B rows, 16B-aligned

__global__ __launch_bounds__(256)
void qkv_gemm_fused(const float* __restrict__ X,
                    const float* __restrict__ Wq, const float* __restrict__ bq, float* __restrict__ Oq,
                    const float* __restrict__ Wk, const float* __restrict__ bk, float* __restrict__ Ok,
                    const float* __restrict__ Wv, const float* __restrict__ bv, float* __restrict__ Ov)
{
    const float* W;  const float* bias;  float* Out;  float scale;
    if (blockIdx.z == 0)      { W = Wq; bias = bq; Out = Oq; scale = 0.125f; }
    else if (blockIdx.z == 1) { W = Wk; bias = bk; Out = Ok; scale = 1.0f;   }
    else                      { W = Wv; bias = bv; Out = Ov; scale = 1.0f;   }

    __shared__ float xs[GBM][GST];
    __shared__ float wsm[GBN][GST];

    const int m0 = blockIdx.y * GBM;
    const int n0 = blockIdx.x * GBN;
    const int tid = threadIdx.x;
    const int tx = tid & 15, ty = tid >> 4;

    float acc[4][4];
    #pragma unroll
    for (int i = 0; i < 4; ++i)
        #pragma unroll
        for (int j = 0; j < 4; ++j) acc[i][j] = 0.f;

    for (int k0 = 0; k0 < DIM; k0 += GBK) {
        #pragma unroll
        for (int p = 0; p < 2; ++p) {
            int f4 = tid + p * 256;
            int row = f4 >> 3;
            int c4 = (f4 & 7) << 2;
            *(float4*)&xs[row][c4]  = *(const float4*)&X[(size_t)(m0 + row) * DIM + k0 + c4];
            *(float4*)&wsm[row][c4] = *(const float4*)&W[(size_t)(n0 + row) * DIM + k0 + c4];
        }
        __syncthreads();
        #pragma unroll
        for (int kk = 0; kk < GBK; kk += 4) {
            float4 a4[4], b4[4];
            #pragma unroll
            for (int i = 0; i < 4; ++i) a4[i] = *(const float4*)&xs[ty + 16 * i][kk];
            #pragma unroll
            for (int j = 0; j < 4; ++j) b4[j] = *(const float4*)&wsm[tx + 16 * j][kk];
            #pragma unroll
            for (int i = 0; i < 4; ++i)
                #pragma unroll
                for (int j = 0; j < 4; ++j) {
                    acc[i][j] = fmaf(a4[i].x, b4[j].x, acc[i][j]);
                    acc[i][j] = fmaf(a4[i].y, b4[j].y, acc[i][j]);
                    acc[i][j] = fmaf(a4[i].z, b4[j].z, acc[i][j]);
                    acc[i][j] = fmaf(a4[i].w, b4[j].w, acc[i][j]);
                }
        }
        __syncthreads();
    }

    #pragma unroll
    for (int i = 0; i < 4; ++i) {
        int row = m0 + ty + 16 * i;
        int b_ = row >> 11;
        int s_ = row & 2047;
        #pragma unroll
        for (int j = 0; j < 4; ++j) {
            int col = n0 + tx + 16 * j;
            int h_ = col >> 6, d_ = col & 63;
            float v = (acc[i][j] + bias[col]) * scale;
            Out[((size_t)((b_ * NH + h_) * QLEN + s_)) * DH + d_] = v;
        }
    }
}

// =====================================================================
// Kernel 2: flash attention.
//   Round 18 score phase: 4-row register blocking on 256 ACTIVE threads
//   (rg=tid>>5 owns rows {rg,rg+8,rg+16,rg+24} x 4 k-slots = 16 scores).
//   Score LDS reads 49152 -> 32768 thread-instrs (-33%); VALU check:
//   1024 FMA x 2cyc = 2048 cyc/SIMD < LDS 6144 -> still LDS-bound.
//   NO new shfl traffic (r15 lesson); butterfly groups stay in wave
//   halves (waves 0-3 hold tids 0-255). All fmaf/max/sum orders are
//   bit-identical to r17 -> wch/M/L/ctx unchanged.
//   TRIPWIRE: VGPR=128 + WRITE_SIZE spike => spill => revert.
//   PV phase + k-partition reduce UNCHANGED.
// =====================================================================
#define QT2 32
#define KC  128
#define NCH (QLEN / KC)   // 16

__device__ __forceinline__ void pv_row(const float4& wr,
                                       const float4& v0, const float4& v1,
                                       const float4& v2, const float4& v3,
                                       float& c0, float& c1, float& c2, float& c3)
{
    c0 = fmaf(wr.x, v0.x, c0); c1 = fmaf(wr.x, v0.y, c1);
    c2 = fmaf(wr.x, v0.z, c2); c3 = fmaf(wr.x, v0.w, c3);
    c0 = fmaf(wr.y, v1.x, c0); c1 = fmaf(wr.y, v1.y, c1);
    c2 = fmaf(wr.y, v1.z, c2); c3 = fmaf(wr.y, v1.w, c3);
    c0 = fmaf(wr.z, v2.x, c0); c1 = fmaf(wr.z, v2.y, c1);
    c2 = fmaf(wr.z, v2.z, c2); c3 = fmaf(wr.z, v2.w, c3);
    c0 = fmaf(wr.w, v3.x, c0); c1 = fmaf(wr.w, v3.y, c1);
    c2 = fmaf(wr.w, v3.z, c2); c3 = fmaf(wr.w, v3.w, c3);
}

__global__ __launch_bounds__(512, 1)
void attn_kernel(const float* __restrict__ Qm, const float* __restrict__ Km,
                 const float* __restrict__ Vm, const int* __restrict__ mask,
                 float* __restrict__ ctx_out, float* __restrict__ MLbuf)
{
    __shared__ float qs[QT2][DH + 4];                 //  8.5 KB
    __shared__ __align__(16) float ks[KC][DH + 4];    // 34 KB (reused as reduce scratch)
    __shared__ float vs[KC][DH];                      // 32 KB
    __shared__ float wch[QT2][132];                   // 16.9 KB
    __shared__ int   msk[KC];
    __shared__ float m_lds[QT2];
    __shared__ float l_lds[QT2];
    __shared__ float scl[QT2];

    const int b   = blockIdx.y;
    const int q0  = blockIdx.x * QT2;
    const int tid = threadIdx.x;
    const int rg  = (tid >> 5) & 7;  // score-phase row group (tid<256)
    const int kt2 = tid & 31;        // score-phase k lane
    const int part = tid >> 7;       // PV k-partition
    const int sub  = tid & 127;
    const int pr   = (sub >> 4) << 2;  // PV row base: 0,4,...,28
    const int pc4  = (sub & 15) << 2;  // PV col base

    #pragma unroll 1
    for (int h = 0; h < NH; ++h) {
        const float* Qh = Qm + (((size_t)b * NH + h) * QLEN + q0) * DH;
        const float* Kh = Km + ((size_t)b * NH + h) * QLEN * DH;
        const float* Vh = Vm + ((size_t)b * NH + h) * QLEN * DH;

        {   // stage q-tile 32x64 (already includes 1/sqrt(dh)); covered by c=0 barrier
            int row = tid >> 4, c4 = (tid & 15) << 2;
            *(float4*)&qs[row][c4] = *(const float4*)&Qh[(size_t)row * DH + c4];
        }
        if (tid < QT2) { m_lds[tid] = -INFINITY; l_lds[tid] = 0.0f; }

        float cvA0 = 0.f, cvA1 = 0.f, cvA2 = 0.f, cvA3 = 0.f;
        float cvB0 = 0.f, cvB1 = 0.f, cvB2 = 0.f, cvB3 = 0.f;
        float cvC0 = 0.f, cvC1 = 0.f, cvC2 = 0.f, cvC3 = 0.f;
        float cvD0 = 0.f, cvD1 = 0.f, cvD2 = 0.f, cvD3 = 0.f;

        #pragma unroll 1
        for (int c = 0; c < NCH; ++c) {
            #pragma unroll
            for (int p = 0; p < 4; ++p) {
                int f4 = tid + p * 512;
                int row = f4 >> 4, c4 = (f4 & 15) << 2;
                *(float4*)&ks[row][c4] = *(const float4*)&Kh[(size_t)(c * KC + row) * DH + c4];
                *(float4*)&vs[row][c4] = *(const float4*)&Vh[(size_t)(c * KC + row) * DH + c4];
            }
            if (tid < KC) msk[tid] = mask[b * QLEN + c * KC + tid];
            __syncthreads();

            if (tid < 256) {
                // ---- scores: rows {rg,rg+8,rg+16,rg+24} x slots kt2+32jj ----
                float s[4][4];
                #pragma unroll
                for (int i = 0; i < 4; ++i)
                    #pragma unroll
                    for (int jj = 0; jj < 4; ++jj) s[i][jj] = 0.f;
                #pragma unroll
                for (int d0 = 0; d0 < DH; d0 += 4) {
                    float4 qv0 = *(const float4*)&qs[rg     ][d0];
                    float4 qv1 = *(const float4*)&qs[rg + 8 ][d0];
                    float4 qv2 = *(const float4*)&qs[rg + 16][d0];
                    float4 qv3 = *(const float4*)&qs[rg + 24][d0];
                    #pragma unroll
                    for (int jj = 0; jj < 4; ++jj) {
                        float4 kv = *(const float4*)&ks[kt2 + 32 * jj][d0];
                        s[0][jj] = fmaf(qv0.x, kv.x, s[0][jj]);
                        s[0][jj] = fmaf(qv0.y, kv.y, s[0][jj]);
                        s[0][jj] = fmaf(qv0.z, kv.z, s[0][jj]);
                        s[0][jj] = fmaf(qv0.w, kv.w, s[0][jj]);
                        s[1][jj] = fmaf(qv1.x, kv.x, s[1][jj]);
                        s[1][jj] = fmaf(qv1.y, kv.y, s[1][jj]);
                        s[1][jj] = fmaf(qv1.z, kv.z, s[1][jj]);
                        s[1][jj] = fmaf(qv1.w, kv.w, s[1][jj]);
                        s[2][jj] = fmaf(qv2.x, kv.x, s[2][jj]);
                        s[2][jj] = fmaf(qv2.y, kv.y, s[2][jj]);
                        s[2][jj] = fmaf(qv2.z, kv.z, s[2][jj]);
                        s[2][jj] = fmaf(qv2.w, kv.w, s[2][jj]);
                        s[3][jj] = fmaf(qv3.x, kv.x, s[3][jj]);
                        s[3][jj] = fmaf(qv3.y, kv.y, s[3][jj]);
                        s[3][jj] = fmaf(qv3.z, kv.z, s[3][jj]);
                        s[3][jj] = fmaf(qv3.w, kv.w, s[3][jj]);
                    }
                }
                float mm[4];
                #pragma unroll
                for (int i = 0; i < 4; ++i) {
                    mm[i] = -INFINITY;
                    #pragma unroll
                    for (int jj = 0; jj < 4; ++jj) {
                        s[i][jj] = msk[kt2 + 32 * jj] ? s[i][jj] : -INFINITY;
                        mm[i] = fmaxf(mm[i], s[i][jj]);
                    }
                }
                // row max over the 32 kt2 lanes (stays within wave half)
                #pragma unroll
                for (int off = 1; off < 32; off <<= 1) {
                    #pragma unroll
                    for (int i = 0; i < 4; ++i)
                        mm[i] = fmaxf(mm[i], __shfl_xor(mm[i], off, 64));
                }
                float ls[4], mnew[4], sc[4];
                #pragma unroll
                for (int i = 0; i < 4; ++i) {
                    int r = rg + 8 * i;
                    float mold = m_lds[r];
                    mnew[i] = fmaxf(mold, mm[i]);
                    sc[i]   = (mnew[i] > -INFINITY) ? __expf(mold - mnew[i]) : 0.0f;
                    float l = 0.f;
                    #pragma unroll
                    for (int jj = 0; jj < 4; ++jj) {
                        float w = (s[i][jj] > -INFINITY) ? __expf(s[i][jj] - mnew[i]) : 0.0f;
                        wch[r][kt2 + 32 * jj] = w;
                        l += w;
                    }
                    ls[i] = l;
                }
                #pragma unroll
                for (int off = 1; off < 32; off <<= 1) {
                    #pragma unroll
                    for (int i = 0; i < 4; ++i)
                        ls[i] += __shfl_xor(ls[i], off, 64);
                }
                if (kt2 == 0) {
                    #pragma unroll
                    for (int i = 0; i < 4; ++i) {
                        int r = rg + 8 * i;
                        l_lds[r] = l_lds[r] * sc[i] + ls[i];
                        m_lds[r] = mnew[i];
                        scl[r]   = sc[i];
                    }
                }
            }
            __syncthreads();   // wch + scl ready

            // ---- PV: all 512 threads; 4x4 tile over k-partition `part` ----
            {
                float sA = scl[pr], sB = scl[pr + 1], sC = scl[pr + 2], sD = scl[pr + 3];
                cvA0 *= sA; cvA1 *= sA; cvA2 *= sA; cvA3 *= sA;
                cvB0 *= sB; cvB1 *= sB; cvB2 *= sB; cvB3 *= sB;
                cvC0 *= sC; cvC1 *= sC; cvC2 *= sC; cvC3 *= sC;
                cvD0 *= sD; cvD1 *= sD; cvD2 *= sD; cvD3 *= sD;
                const int kbase = part * 32;
                #pragma unroll 2
                for (int kk = 0; kk < 32; kk += 4) {
                    int k0 = kbase + kk;
                    float4 wA = *(const float4*)&wch[pr    ][k0];
                    float4 wB = *(const float4*)&wch[pr + 1][k0];
                    float4 wC = *(const float4*)&wch[pr + 2][k0];
                    float4 wD = *(const float4*)&wch[pr + 3][k0];
                    float4 v0 = *(const float4*)&vs[k0    ][pc4];
                    float4 v1 = *(const float4*)&vs[k0 + 1][pc4];
                    float4 v2 = *(const float4*)&vs[k0 + 2][pc4];
                    float4 v3 = *(const float4*)&vs[k0 + 3][pc4];
                    pv_row(wA, v0, v1, v2, v3, cvA0, cvA1, cvA2, cvA3);
                    pv_row(wB, v0, v1, v2, v3, cvB0, cvB1, cvB2, cvB3);
                    pv_row(wC, v0, v1, v2, v3, cvC0, cvC1, cvC2, cvC3);
                    pv_row(wD, v0, v1, v2, v3, cvD0, cvD1, cvD2, cvD3);
                }
            }
            __syncthreads();   // before next chunk overwrites ks/vs/wch
        }

        // ---- reduce the 4 k-partition partials (LDS scratch = ks region) ----
        float4* red4 = (float4*)&ks[0][0];
        if (part != 0) {
            int base = sub * 13 + (part - 1) * 4;
            red4[base + 0] = make_float4(cvA0, cvA1, cvA2, cvA3);
            red4[base + 1] = make_float4(cvB0, cvB1, cvB2, cvB3);
            red4[base + 2] = make_float4(cvC0, cvC1, cvC2, cvC3);
            red4[base + 3] = make_float4(cvD0, cvD1, cvD2, cvD3);
        }
        __syncthreads();
        if (part == 0) {
            #pragma unroll
            for (int p = 0; p < 3; ++p) {
                int base = sub * 13 + p * 4;
                float4 rA = red4[base + 0], rB = red4[base + 1];
                float4 rC = red4[base + 2], rD = red4[base + 3];
                cvA0 += rA.x; cvA1 += rA.y; cvA2 += rA.z; cvA3 += rA.w;
                cvB0 += rB.x; cvB1 += rB.y; cvB2 += rB.z; cvB3 += rB.w;
                cvC0 += rC.x; cvC1 += rC.y; cvC2 += rC.z; cvC3 += rC.w;
                cvD0 += rD.x; cvD1 += rD.y; cvD2 += rD.z; cvD3 += rD.w;
            }
            float LA = l_lds[pr], LB = l_lds[pr + 1], LC = l_lds[pr + 2], LD = l_lds[pr + 3];
            float* base = ctx_out + ((size_t)(b * QLEN + q0)) * DIM + h * DH + pc4;
            *(float4*)&base[(size_t)(pr    ) * DIM] = make_float4(cvA0 / LA, cvA1 / LA, cvA2 / LA, cvA3 / LA);
            *(float4*)&base[(size_t)(pr + 1) * DIM] = make_float4(cvB0 / LB, cvB1 / LB, cvB2 / LB, cvB3 / LB);
            *(float4*)&base[(size_t)(pr + 2) * DIM] = make_float4(cvC0 / LC, cvC1 / LC, cvC2 / LC, cvC3 / LC);
            *(float4*)&base[(size_t)(pr + 3) * DIM] = make_float4(cvD0 / LD, cvD1 / LD, cvD2 / LD, cvD3 / LD);
        }
        if (tid < QT2) {   // side-channel for the hsum/argmax kernel
            float* mlp = MLbuf + (((size_t)(b * QLEN + q0 + tid)) * NH + h) * 2;
            mlp[0] = m_lds[tid];
            mlp[1] = l_lds[tid];
        }
        __syncthreads();   // reduce-scratch/L/M reads done before next head
    }
}

// =====================================================================
// Kernel 2b: head-summed softmax weights -> argmax (QT2=32).
//   UNCHANGED from round 17 (__expf + staged reciprocal — validated).
// =====================================================================
__global__ __launch_bounds__(512, 4)
void hsum_argmax_kernel(const float* __restrict__ Qm, const float* __restrict__ Km,
                        const int* __restrict__ mask, const float* __restrict__ MLbuf,
                        float* __restrict__ idx_out)
{
    __shared__ float qs[QT2][DH + 4];    //  8.7 KB (restaged per h)
    __shared__ float ks[KC][DH + 4];     // 34 KB
    __shared__ float Mh[NH][QT2];        //  2 KB
    __shared__ float Lh[NH][QT2];        //  2 KB  (stores 1/L)
    __shared__ int   msk[KC];
    __shared__ float rv[2][16][32];      //  4 KB
    __shared__ int   ri[2][16][32];      //  4 KB

    const int b   = blockIdx.y;
    const int q0  = blockIdx.x * QT2;
    const int tid = threadIdx.x;
    const int qp  = tid >> 5;        // 0..15
    const int kt2 = tid & 31;        // 0..31

    {   // stage per-(row,h) softmax stats: 512 = 16h x 32rows
        int h = tid >> 5, rr = tid & 31;
        const float* mlp = MLbuf + (((size_t)(b * QLEN + q0 + rr)) * NH + h) * 2;
        Mh[h][rr] = mlp[0];
        Lh[h][rr] = 1.0f / mlp[1];
    }   // visibility covered by the first staging barrier below

    float bv0 = -1.0f, bv1 = -1.0f; int bk0 = 0, bk1 = 0;
    #pragma unroll 1
    for (int c = 0; c < NCH; ++c) {
        float a00 = 0.f, a01 = 0.f, a02 = 0.f, a03 = 0.f;   // row qp
        float a10 = 0.f, a11 = 0.f, a12 = 0.f, a13 = 0.f;   // row qp+16
        #pragma unroll 1
        for (int h = 0; h < NH; ++h) {
            __syncthreads();          // previous readers of ks/qs/msk done
            const float* Kh = Km + ((size_t)b * NH + h) * QLEN * DH;
            #pragma unroll
            for (int p = 0; p < 4; ++p) {
                int f4 = tid + p * 512;
                int row = f4 >> 4, c4 = (f4 & 15) << 2;
                *(float4*)&ks[row][c4] = *(const float4*)&Kh[(size_t)(c * KC + row) * DH + c4];
            }
            {   // stage q-tile 32x64 for head h
                const float* Qh = Qm + (((size_t)b * NH + h) * QLEN + q0) * DH;
                int row = tid >> 4, c4 = (tid & 15) << 2;
                *(float4*)&qs[row][c4] = *(const float4*)&Qh[(size_t)row * DH + c4];
            }
            if (h == 0 && tid < KC) msk[tid] = mask[b * QLEN + c * KC + tid];
            __syncthreads();

            float s0[4], s1[4];
            #pragma unroll
            for (int jj = 0; jj < 4; ++jj) { s0[jj] = 0.f; s1[jj] = 0.f; }
            #pragma unroll 4
            for (int d0 = 0; d0 < DH; d0 += 4) {
                float4 qv0 = *(const float4*)&qs[qp][d0];
                float4 qv1 = *(const float4*)&qs[qp + 16][d0];
                #pragma unroll
                for (int jj = 0; jj < 4; ++jj) {
                    float4 kv = *(const float4*)&ks[kt2 + 32 * jj][d0];
                    s0[jj] = fmaf(qv0.x, kv.x, s0[jj]);
                    s0[jj] = fmaf(qv0.y, kv.y, s0[jj]);
                    s0[jj] = fmaf(qv0.z, kv.z, s0[jj]);
                    s0[jj] = fmaf(qv0.w, kv.w, s0[jj]);
                    s1[jj] = fmaf(qv1.x, kv.x, s1[jj]);
                    s1[jj] = fmaf(qv1.y, kv.y, s1[jj]);
                    s1[jj] = fmaf(qv1.z, kv.z, s1[jj]);
                    s1[jj] = fmaf(qv1.w, kv.w, s1[jj]);
                }
            }
            const float Mv0 = Mh[h][qp],      rL0 = Lh[h][qp];
            const float Mv1 = Mh[h][qp + 16], rL1 = Lh[h][qp + 16];
            int mk0 = msk[kt2], mk1 = msk[kt2 + 32], mk2 = msk[kt2 + 64], mk3 = msk[kt2 + 96];
            a00 += mk0 ? __expf(s0[0] - Mv0) * rL0 : 0.f;
            a01 += mk1 ? __expf(s0[1] - Mv0) * rL0 : 0.f;
            a02 += mk2 ? __expf(s0[2] - Mv0) * rL0 : 0.f;
            a03 += mk3 ? __expf(s0[3] - Mv0) * rL0 : 0.f;
            a10 += mk0 ? __expf(s1[0] - Mv1) * rL1 : 0.f;
            a11 += mk1 ? __expf(s1[1] - Mv1) * rL1 : 0.f;
            a12 += mk2 ? __expf(s1[2] - Mv1) * rL1 : 0.f;
            a13 += mk3 ? __expf(s1[3] - Mv1) * rL1 : 0.f;
        }
        // k ascending across (c, jj) for fixed kt2 -> '>' keeps first index
        int kbase = c * KC + kt2;
        if (a00 > bv0) { bv0 = a00; bk0 = kbase;      }
        if (a01 > bv0) { bv0 = a01; bk0 = kbase + 32; }
        if (a02 > bv0) { bv0 = a02; bk0 = kbase + 64; }
        if (a03 > bv0) { bv0 = a03; bk0 = kbase + 96; }
        if (a10 > bv1) { bv1 = a10; bk1 = kbase;      }
        if (a11 > bv1) { bv1 = a11; bk1 = kbase + 32; }
        if (a12 > bv1) { bv1 = a12; bk1 = kbase + 64; }
        if (a13 > bv1) { bv1 = a13; bk1 = kbase + 96; }
    }

    rv[0][qp][kt2] = bv0; ri[0][qp][kt2] = bk0;
    rv[1][qp][kt2] = bv1; ri[1][qp][kt2] = bk1;
    __syncthreads();
    if (tid < QT2) {                 // one thread finalizes each row
        int half = tid >> 4, qq = tid & 15;
        float BV = -1.0f; int BKi = 1 << 30;
        for (int i = 0; i < 32; ++i) {
            float v = rv[half][qq][i];
            int  kk = ri[half][qq][i];
            if (v > BV || (v == BV && kk < BKi)) { BV = v; BKi = kk; }
        }
        idx_out[b * QLEN + q0 + half * 16 + qq] = (float)BKi;
    }
}

// =====================================================================
// Kernel 3: output projection  out = CTX @ Wo^T + bo
//   UNCHANGED from round 17 (full-reuse tiled GEMM, CTX in ws).
// =====================================================================
__global__ __launch_bounds__(256)
void oproj_gemm(const float* __restrict__ X, const float* __restrict__ W,
                const float* __restrict__ bias, float* __restrict__ Out)
{
    __shared__ float xs[GBM][GST];
    __shared__ float wsm[GBN][GST];

    const int m0 = blockIdx.y * GBM;
    const int n0 = blockIdx.x * GBN;
    const int tid = threadIdx.x;
    const int tx = tid & 15, ty = tid >> 4;

    float acc[4][4];
    #pragma unroll
    for (int i = 0; i < 4; ++i)
        #pragma unroll
        for (int j = 0; j < 4; ++j) acc[i][j] = 0.f;

    for (int k0 = 0; k0 < DIM; k0 += GBK) {
        #pragma unroll
        for (int p = 0; p < 2; ++p) {
            int f4 = tid + p * 256;
            int row = f4 >> 3;
            int c4 = (f4 & 7) << 2;
            *(float4*)&xs[row][c4]  = *(const float4*)&X[(size_t)(m0 + row) * DIM + k0 + c4];
            *(float4*)&wsm[row][c4] = *(const float4*)&W[(size_t)(n0 + row) * DIM + k0 + c4];
        }
        __syncthreads();
        #pragma unroll
        for (int kk = 0; kk < GBK; kk += 4) {
            float4 a4[4], b4[4];
            #pragma unroll
            for (int i = 0; i < 4; ++i) a4[i] = *(const float4*)&xs[ty + 16 * i][kk];
            #pragma unroll
            for (int j = 0; j < 4; ++j) b4[j] = *(const float4*)&wsm[tx + 16 * j][kk];
            #pragma unroll
            for (int i = 0; i < 4; ++i)
                #pragma unroll
                for (int j = 0; j < 4; ++j) {
                    acc[i][j] = fmaf(a4[i].x, b4[j].x, acc[i][j]);
                    acc[i][j] = fmaf(a4[i].y, b4[j].y, acc[i][j]);
                    acc[i][j] = fmaf(a4[i].z, b4[j].z, acc[i][j]);
                    acc[i][j] = fmaf(a4[i].w, b4[j].w, acc[i][j]);
                }
        }
        __syncthreads();
    }

    #pragma unroll
    for (int i = 0; i < 4; ++i) {
        int row = m0 + ty + 16 * i;
        #pragma unroll
        for (int j = 0; j < 4; ++j) {
            int col = n0 + tx + 16 * j;
            Out[(size_t)row * DIM + col] = acc[i][j] + bias[col];
        }
    }
}

// =====================================================================
extern "C" void kernel_launch(void* const* d_in, const int* in_sizes, int n_in,
                              void* d_out, int out_size, void* d_ws, size_t ws_size,
                              hipStream_t stream)
{
    (void)in_sizes; (void)n_in; (void)out_size; (void)ws_size;
    const float* query = (const float*)d_in[0];
    const int*   mask  = (const int*)  d_in[1];
    const float* Wq = (const float*)d_in[2];
    const float* bq = (const float*)d_in[3];
    const float* Wk = (const float*)d_in[4];
    const float* bk = (const float*)d_in[5];
    const float* Wv = (const float*)d_in[6];
    const float* bv = (const float*)d_in[7];
    const float* Wo = (const float*)d_in[8];
    const float* bo = (const float*)d_in[9];

    float* out = (float*)d_out;
    const size_t NTOK = (size_t)BS * QLEN;     // 8192
    const size_t QKV  = NTOK * DIM;
    const size_t MLSZ = NTOK * NH * 2;
    float* Qw  = (float*)d_ws;                 // ws: 3x32 MB + 1 MB + 32 MB = 129 MB
    float* Kw  = Qw + QKV;
    float* Vw  = Kw + QKV;
    float* ML  = Vw + QKV;                     // [NTOK][NH][2] f32
    float* CTX = ML + MLSZ;                    // [NTOK][DIM] f32

    dim3 gemm_grid3(DIM / GBN, (BS * QLEN) / GBM, 3);   // (16, 128, 3)
    qkv_gemm_fused<<<gemm_grid3, dim3(256), 0, stream>>>(
        query, Wq, bq, Qw, Wk, bk, Kw, Wv, bv, Vw);

    float* idx = out + NTOK * DIM;     // argmax output tail
    attn_kernel<<<dim3(QLEN / QT2, BS), dim3(512), 0, stream>>>(Qw, Kw, Vw, mask, CTX, ML);
    hsum_argmax_kernel<<<dim3(QLEN / QT2, BS), dim3(512), 0, stream>>>(Qw, Kw, mask, ML, idx);

    dim3 gemm_grid(DIM / GBN, (BS * QLEN) / GBM);       // (16, 128)
    oproj_gemm<<<gemm_grid, dim3(256), 0, stream>>>(CTX, Wo, bo, out);
}

// Round 19
// 3339.452 us; speedup vs baseline: 7.3144x; 7.3144x over previous
//
#include <hip/hip_runtime.h>
#include <math.h>

#define BS   4
#define QLEN 2048
#define DIM  1024
#define NH   16
#define DH   64

// =====================================================================
// Kernel 1: fused QKV projection GEMM (gridDim.z selects Q/K/V).
//   UNCHANGED from round 17.
// =====================================================================
#define GBM 64
#define GBN 64
#define GBK 32
#define GST (GBK + 4)    // 36 floats: 144B rows, 16B-aligned

__global__ __launch_bounds__(256)
void qkv_gemm_fused(const float* __restrict__ X,
                    const float* __restrict__ Wq, const float* __restrict__ bq, float* __restrict__ Oq,
                    const float* __restrict__ Wk, const float* __restrict__ bk, float* __restrict__ Ok,
                    const float* __restrict__ Wv, const float* __restrict__ bv, float* __restrict__ Ov)
{
    const float* W;  const float* bias;  float* Out;  float scale;
    if (blockIdx.z == 0)      { W = Wq; bias = bq; Out = Oq; scale = 0.125f; }
    else if (blockIdx.z == 1) { W = Wk; bias = bk; Out = Ok; scale = 1.0f;   }
    else                      { W = Wv; bias = bv; Out = Ov; scale = 1.0f;   }

    __shared__ float xs[GBM][GST];
    __shared__ float wsm[GBN][GST];

    const int m0 = blockIdx.y * GBM;
    const int n0 = blockIdx.x * GBN;
    const int tid = threadIdx.x;
    const int tx = tid & 15, ty = tid >> 4;

    float acc[4][4];
    #pragma unroll
    for (int i = 0; i < 4; ++i)
        #pragma unroll
        for (int j = 0; j < 4; ++j) acc[i][j] = 0.f;

    for (int k0 = 0; k0 < DIM; k0 += GBK) {
        #pragma unroll
        for (int p = 0; p < 2; ++p) {
            int f4 = tid + p * 256;
            int row = f4 >> 3;
            int c4 = (f4 & 7) << 2;
            *(float4*)&xs[row][c4]  = *(const float4*)&X[(size_t)(m0 + row) * DIM + k0 + c4];
            *(float4*)&wsm[row][c4] = *(const float4*)&W[(size_t)(n0 + row) * DIM + k0 + c4];
        }
        __syncthreads();
        #pragma unroll
        for (int kk = 0; kk < GBK; kk += 4) {
            float4 a4[4], b4[4];
            #pragma unroll
            for (int i = 0; i < 4; ++i) a4[i] = *(const float4*)&xs[ty + 16 * i][kk];
            #pragma unroll
            for (int j = 0; j < 4; ++j) b4[j] = *(const float4*)&wsm[tx + 16 * j][kk];
            #pragma unroll
            for (int i = 0; i < 4; ++i)
                #pragma unroll
                for (int j = 0; j < 4; ++j) {
                    acc[i][j] = fmaf(a4[i].x, b4[j].x, acc[i][j]);
                    acc[i][j] = fmaf(a4[i].y, b4[j].y, acc[i][j]);
                    acc[i][j] = fmaf(a4[i].z, b4[j].z, acc[i][j]);
                    acc[i][j] = fmaf(a4[i].w, b4[j].w, acc[i][j]);
                }
        }
        __syncthreads();
    }

    #pragma unroll
    for (int i = 0; i < 4; ++i) {
        int row = m0 + ty + 16 * i;
        int b_ = row >> 11;
        int s_ = row & 2047;
        #pragma unroll
        for (int j = 0; j < 4; ++j) {
            int col = n0 + tx + 16 * j;
            int h_ = col >> 6, d_ = col & 63;
            float v = (acc[i][j] + bias[col]) * scale;
            Out[((size_t)((b_ * NH + h_) * QLEN + s_)) * DH + d_] = v;
        }
    }
}

// =====================================================================
// Kernel 2: flash attention — REVERTED to the round-17 version (1.66 ms,
//   VGPR 96, zero conflicts). r18 lesson (3rd confirmation): any score-
//   phase restructure adding >=16 live registers spills at the 512-thread
//   128-VGPR ceiling (r8, r15, r18). The 2-row score phase is the
//   practical optimum for this block shape.
// =====================================================================
#define QT2 32
#define KC  128
#define NCH (QLEN / KC)   // 16

__device__ __forceinline__ void pv_row(const float4& wr,
                                       const float4& v0, const float4& v1,
                                       const float4& v2, const float4& v3,
                                       float& c0, float& c1, float& c2, float& c3)
{
    c0 = fmaf(wr.x, v0.x, c0); c1 = fmaf(wr.x, v0.y, c1);
    c2 = fmaf(wr.x, v0.z, c2); c3 = fmaf(wr.x, v0.w, c3);
    c0 = fmaf(wr.y, v1.x, c0); c1 = fmaf(wr.y, v1.y, c1);
    c2 = fmaf(wr.y, v1.z, c2); c3 = fmaf(wr.y, v1.w, c3);
    c0 = fmaf(wr.z, v2.x, c0); c1 = fmaf(wr.z, v2.y, c1);
    c2 = fmaf(wr.z, v2.z, c2); c3 = fmaf(wr.z, v2.w, c3);
    c0 = fmaf(wr.w, v3.x, c0); c1 = fmaf(wr.w, v3.y, c1);
    c2 = fmaf(wr.w, v3.z, c2); c3 = fmaf(wr.w, v3.w, c3);
}

__global__ __launch_bounds__(512, 1)
void attn_kernel(const float* __restrict__ Qm, const float* __restrict__ Km,
                 const float* __restrict__ Vm, const int* __restrict__ mask,
                 float* __restrict__ ctx_out, float* __restrict__ MLbuf)
{
    __shared__ float qs[QT2][DH + 4];                 //  8.5 KB
    __shared__ __align__(16) float ks[KC][DH + 4];    // 34 KB (reused as reduce scratch)
    __shared__ float vs[KC][DH];                      // 32 KB
    __shared__ float wch[QT2][132];                   // 16.9 KB
    __shared__ int   msk[KC];
    __shared__ float m_lds[QT2];
    __shared__ float l_lds[QT2];
    __shared__ float scl[QT2];

    const int b   = blockIdx.y;
    const int q0  = blockIdx.x * QT2;
    const int tid = threadIdx.x;
    const int qp  = tid >> 5;        // 0..15  (score-phase row pair base)
    const int kt2 = tid & 31;        // 0..31  (score-phase k lane)
    const int part = tid >> 7;       // 0..3   (PV k-partition)
    const int sub  = tid & 127;
    const int pr   = (sub >> 4) << 2;  // PV row base: 0,4,...,28
    const int pc4  = (sub & 15) << 2;  // PV col base

    #pragma unroll 1
    for (int h = 0; h < NH; ++h) {
        const float* Qh = Qm + (((size_t)b * NH + h) * QLEN + q0) * DH;
        const float* Kh = Km + ((size_t)b * NH + h) * QLEN * DH;
        const float* Vh = Vm + ((size_t)b * NH + h) * QLEN * DH;

        {   // stage q-tile 32x64 (already includes 1/sqrt(dh)); covered by c=0 barrier
            int row = tid >> 4, c4 = (tid & 15) << 2;
            *(float4*)&qs[row][c4] = *(const float4*)&Qh[(size_t)row * DH + c4];
        }
        if (tid < QT2) { m_lds[tid] = -INFINITY; l_lds[tid] = 0.0f; }

        float cvA0 = 0.f, cvA1 = 0.f, cvA2 = 0.f, cvA3 = 0.f;
        float cvB0 = 0.f, cvB1 = 0.f, cvB2 = 0.f, cvB3 = 0.f;
        float cvC0 = 0.f, cvC1 = 0.f, cvC2 = 0.f, cvC3 = 0.f;
        float cvD0 = 0.f, cvD1 = 0.f, cvD2 = 0.f, cvD3 = 0.f;

        #pragma unroll 1
        for (int c = 0; c < NCH; ++c) {
            #pragma unroll
            for (int p = 0; p < 4; ++p) {
                int f4 = tid + p * 512;
                int row = f4 >> 4, c4 = (f4 & 15) << 2;
                *(float4*)&ks[row][c4] = *(const float4*)&Kh[(size_t)(c * KC + row) * DH + c4];
                *(float4*)&vs[row][c4] = *(const float4*)&Vh[(size_t)(c * KC + row) * DH + c4];
            }
            if (tid < KC) msk[tid] = mask[b * QLEN + c * KC + tid];
            __syncthreads();

            // ---- scores: rows {qp, qp+16} x slots kt2+32jj, ascending-d chain ----
            float s0[4], s1[4];
            #pragma unroll
            for (int jj = 0; jj < 4; ++jj) { s0[jj] = 0.f; s1[jj] = 0.f; }
            #pragma unroll
            for (int d0 = 0; d0 < DH; d0 += 4) {
                float4 qv0 = *(const float4*)&qs[qp][d0];
                float4 qv1 = *(const float4*)&qs[qp + 16][d0];
                #pragma unroll
                for (int jj = 0; jj < 4; ++jj) {
                    float4 kv = *(const float4*)&ks[kt2 + 32 * jj][d0];
                    s0[jj] = fmaf(qv0.x, kv.x, s0[jj]);
                    s0[jj] = fmaf(qv0.y, kv.y, s0[jj]);
                    s0[jj] = fmaf(qv0.z, kv.z, s0[jj]);
                    s0[jj] = fmaf(qv0.w, kv.w, s0[jj]);
                    s1[jj] = fmaf(qv1.x, kv.x, s1[jj]);
                    s1[jj] = fmaf(qv1.y, kv.y, s1[jj]);
                    s1[jj] = fmaf(qv1.z, kv.z, s1[jj]);
                    s1[jj] = fmaf(qv1.w, kv.w, s1[jj]);
                }
            }
            float mm0 = -INFINITY, mm1 = -INFINITY;
            #pragma unroll
            for (int jj = 0; jj < 4; ++jj) {
                s0[jj] = msk[kt2 + 32 * jj] ? s0[jj] : -INFINITY;
                s1[jj] = msk[kt2 + 32 * jj] ? s1[jj] : -INFINITY;
                mm0 = fmaxf(mm0, s0[jj]);
                mm1 = fmaxf(mm1, s1[jj]);
            }
            #pragma unroll
            for (int off = 1; off < 32; off <<= 1) {
                mm0 = fmaxf(mm0, __shfl_xor(mm0, off, 64));
                mm1 = fmaxf(mm1, __shfl_xor(mm1, off, 64));
            }
            float mold0 = m_lds[qp], mold1 = m_lds[qp + 16];
            float mnew0 = fmaxf(mold0, mm0), mnew1 = fmaxf(mold1, mm1);
            float sc0 = (mnew0 > -INFINITY) ? __expf(mold0 - mnew0) : 0.0f;
            float sc1 = (mnew1 > -INFINITY) ? __expf(mold1 - mnew1) : 0.0f;
            float ls0 = 0.f, ls1 = 0.f;
            #pragma unroll
            for (int jj = 0; jj < 4; ++jj) {
                float w0 = (s0[jj] > -INFINITY) ? __expf(s0[jj] - mnew0) : 0.0f;
                float w1 = (s1[jj] > -INFINITY) ? __expf(s1[jj] - mnew1) : 0.0f;
                wch[qp][kt2 + 32 * jj]      = w0;
                wch[qp + 16][kt2 + 32 * jj] = w1;
                ls0 += w0;
                ls1 += w1;
            }
            #pragma unroll
            for (int off = 1; off < 32; off <<= 1) {
                ls0 += __shfl_xor(ls0, off, 64);
                ls1 += __shfl_xor(ls1, off, 64);
            }
            if (kt2 == 0) {
                l_lds[qp]      = l_lds[qp]      * sc0 + ls0;
                l_lds[qp + 16] = l_lds[qp + 16] * sc1 + ls1;
                m_lds[qp]      = mnew0;
                m_lds[qp + 16] = mnew1;
                scl[qp]        = sc0;
                scl[qp + 16]   = sc1;
            }
            __syncthreads();   // wch + scl ready

            // ---- PV: all 512 threads; 4x4 tile over k-partition `part` ----
            {
                float sA = scl[pr], sB = scl[pr + 1], sC = scl[pr + 2], sD = scl[pr + 3];
                cvA0 *= sA; cvA1 *= sA; cvA2 *= sA; cvA3 *= sA;
                cvB0 *= sB; cvB1 *= sB; cvB2 *= sB; cvB3 *= sB;
                cvC0 *= sC; cvC1 *= sC; cvC2 *= sC; cvC3 *= sC;
                cvD0 *= sD; cvD1 *= sD; cvD2 *= sD; cvD3 *= sD;
                const int kbase = part * 32;
                #pragma unroll 2
                for (int kk = 0; kk < 32; kk += 4) {
                    int k0 = kbase + kk;
                    float4 wA = *(const float4*)&wch[pr    ][k0];
                    float4 wB = *(const float4*)&wch[pr + 1][k0];
                    float4 wC = *(const float4*)&wch[pr + 2][k0];
                    float4 wD = *(const float4*)&wch[pr + 3][k0];
                    float4 v0 = *(const float4*)&vs[k0    ][pc4];
                    float4 v1 = *(const float4*)&vs[k0 + 1][pc4];
                    float4 v2 = *(const float4*)&vs[k0 + 2][pc4];
                    float4 v3 = *(const float4*)&vs[k0 + 3][pc4];
                    pv_row(wA, v0, v1, v2, v3, cvA0, cvA1, cvA2, cvA3);
                    pv_row(wB, v0, v1, v2, v3, cvB0, cvB1, cvB2, cvB3);
                    pv_row(wC, v0, v1, v2, v3, cvC0, cvC1, cvC2, cvC3);
                    pv_row(wD, v0, v1, v2, v3, cvD0, cvD1, cvD2, cvD3);
                }
            }
            __syncthreads();   // before next chunk overwrites ks/vs/wch
        }

        // ---- reduce the 4 k-partition partials (LDS scratch = ks region) ----
        float4* red4 = (float4*)&ks[0][0];
        if (part != 0) {
            int base = sub * 13 + (part - 1) * 4;
            red4[base + 0] = make_float4(cvA0, cvA1, cvA2, cvA3);
            red4[base + 1] = make_float4(cvB0, cvB1, cvB2, cvB3);
            red4[base + 2] = make_float4(cvC0, cvC1, cvC2, cvC3);
            red4[base + 3] = make_float4(cvD0, cvD1, cvD2, cvD3);
        }
        __syncthreads();
        if (part == 0) {
            #pragma unroll
            for (int p = 0; p < 3; ++p) {
                int base = sub * 13 + p * 4;
                float4 rA = red4[base + 0], rB = red4[base + 1];
                float4 rC = red4[base + 2], rD = red4[base + 3];
                cvA0 += rA.x; cvA1 += rA.y; cvA2 += rA.z; cvA3 += rA.w;
                cvB0 += rB.x; cvB1 += rB.y; cvB2 += rB.z; cvB3 += rB.w;
                cvC0 += rC.x; cvC1 += rC.y; cvC2 += rC.z; cvC3 += rC.w;
                cvD0 += rD.x; cvD1 += rD.y; cvD2 += rD.z; cvD3 += rD.w;
            }
            float LA = l_lds[pr], LB = l_lds[pr + 1], LC = l_lds[pr + 2], LD = l_lds[pr + 3];
            float* base = ctx_out + ((size_t)(b * QLEN + q0)) * DIM + h * DH + pc4;
            *(float4*)&base[(size_t)(pr    ) * DIM] = make_float4(cvA0 / LA, cvA1 / LA, cvA2 / LA, cvA3 / LA);
            *(float4*)&base[(size_t)(pr + 1) * DIM] = make_float4(cvB0 / LB, cvB1 / LB, cvB2 / LB, cvB3 / LB);
            *(float4*)&base[(size_t)(pr + 2) * DIM] = make_float4(cvC0 / LC, cvC1 / LC, cvC2 / LC, cvC3 / LC);
            *(float4*)&base[(size_t)(pr + 3) * DIM] = make_float4(cvD0 / LD, cvD1 / LD, cvD2 / LD, cvD3 / LD);
        }
        if (tid < QT2) {   // side-channel for the hsum/argmax kernel
            float* mlp = MLbuf + (((size_t)(b * QLEN + q0 + tid)) * NH + h) * 2;
            mlp[0] = m_lds[tid];
            mlp[1] = l_lds[tid];
        }
        __syncthreads();   // reduce-scratch/L/M reads done before next head
    }
}

// =====================================================================
// Kernel 2b: head-summed softmax weights -> argmax (QT2=32).
//   UNCHANGED from round 17 (__expf + staged reciprocal — validated).
// =====================================================================
__global__ __launch_bounds__(512, 4)
void hsum_argmax_kernel(const float* __restrict__ Qm, const float* __restrict__ Km,
                        const int* __restrict__ mask, const float* __restrict__ MLbuf,
                        float* __restrict__ idx_out)
{
    __shared__ float qs[QT2][DH + 4];    //  8.7 KB (restaged per h)
    __shared__ float ks[KC][DH + 4];     // 34 KB
    __shared__ float Mh[NH][QT2];        //  2 KB
    __shared__ float Lh[NH][QT2];        //  2 KB  (stores 1/L)
    __shared__ int   msk[KC];
    __shared__ float rv[2][16][32];      //  4 KB
    __shared__ int   ri[2][16][32];      //  4 KB

    const int b   = blockIdx.y;
    const int q0  = blockIdx.x * QT2;
    const int tid = threadIdx.x;
    const int qp  = tid >> 5;        // 0..15
    const int kt2 = tid & 31;        // 0..31

    {   // stage per-(row,h) softmax stats: 512 = 16h x 32rows
        int h = tid >> 5, rr = tid & 31;
        const float* mlp = MLbuf + (((size_t)(b * QLEN + q0 + rr)) * NH + h) * 2;
        Mh[h][rr] = mlp[0];
        Lh[h][rr] = 1.0f / mlp[1];
    }   // visibility covered by the first staging barrier below

    float bv0 = -1.0f, bv1 = -1.0f; int bk0 = 0, bk1 = 0;
    #pragma unroll 1
    for (int c = 0; c < NCH; ++c) {
        float a00 = 0.f, a01 = 0.f, a02 = 0.f, a03 = 0.f;   // row qp
        float a10 = 0.f, a11 = 0.f, a12 = 0.f, a13 = 0.f;   // row qp+16
        #pragma unroll 1
        for (int h = 0; h < NH; ++h) {
            __syncthreads();          // previous readers of ks/qs/msk done
            const float* Kh = Km + ((size_t)b * NH + h) * QLEN * DH;
            #pragma unroll
            for (int p = 0; p < 4; ++p) {
                int f4 = tid + p * 512;
                int row = f4 >> 4, c4 = (f4 & 15) << 2;
                *(float4*)&ks[row][c4] = *(const float4*)&Kh[(size_t)(c * KC + row) * DH + c4];
            }
            {   // stage q-tile 32x64 for head h
                const float* Qh = Qm + (((size_t)b * NH + h) * QLEN + q0) * DH;
                int row = tid >> 4, c4 = (tid & 15) << 2;
                *(float4*)&qs[row][c4] = *(const float4*)&Qh[(size_t)row * DH + c4];
            }
            if (h == 0 && tid < KC) msk[tid] = mask[b * QLEN + c * KC + tid];
            __syncthreads();

            float s0[4], s1[4];
            #pragma unroll
            for (int jj = 0; jj < 4; ++jj) { s0[jj] = 0.f; s1[jj] = 0.f; }
            #pragma unroll 4
            for (int d0 = 0; d0 < DH; d0 += 4) {
                float4 qv0 = *(const float4*)&qs[qp][d0];
                float4 qv1 = *(const float4*)&qs[qp + 16][d0];
                #pragma unroll
                for (int jj = 0; jj < 4; ++jj) {
                    float4 kv = *(const float4*)&ks[kt2 + 32 * jj][d0];
                    s0[jj] = fmaf(qv0.x, kv.x, s0[jj]);
                    s0[jj] = fmaf(qv0.y, kv.y, s0[jj]);
                    s0[jj] = fmaf(qv0.z, kv.z, s0[jj]);
                    s0[jj] = fmaf(qv0.w, kv.w, s0[jj]);
                    s1[jj] = fmaf(qv1.x, kv.x, s1[jj]);
                    s1[jj] = fmaf(qv1.y, kv.y, s1[jj]);
                    s1[jj] = fmaf(qv1.z, kv.z, s1[jj]);
                    s1[jj] = fmaf(qv1.w, kv.w, s1[jj]);
                }
            }
            const float Mv0 = Mh[h][qp],      rL0 = Lh[h][qp];
            const float Mv1 = Mh[h][qp + 16], rL1 = Lh[h][qp + 16];
            int mk0 = msk[kt2], mk1 = msk[kt2 + 32], mk2 = msk[kt2 + 64], mk3 = msk[kt2 + 96];
            a00 += mk0 ? __expf(s0[0] - Mv0) * rL0 : 0.f;
            a01 += mk1 ? __expf(s0[1] - Mv0) * rL0 : 0.f;
            a02 += mk2 ? __expf(s0[2] - Mv0) * rL0 : 0.f;
            a03 += mk3 ? __expf(s0[3] - Mv0) * rL0 : 0.f;
            a10 += mk0 ? __expf(s1[0] - Mv1) * rL1 : 0.f;
            a11 += mk1 ? __expf(s1[1] - Mv1) * rL1 : 0.f;
            a12 += mk2 ? __expf(s1[2] - Mv1) * rL1 : 0.f;
            a13 += mk3 ? __expf(s1[3] - Mv1) * rL1 : 0.f;
        }
        // k ascending across (c, jj) for fixed kt2 -> '>' keeps first index
        int kbase = c * KC + kt2;
        if (a00 > bv0) { bv0 = a00; bk0 = kbase;      }
        if (a01 > bv0) { bv0 = a01; bk0 = kbase + 32; }
        if (a02 > bv0) { bv0 = a02; bk0 = kbase + 64; }
        if (a03 > bv0) { bv0 = a03; bk0 = kbase + 96; }
        if (a10 > bv1) { bv1 = a10; bk1 = kbase;      }
        if (a11 > bv1) { bv1 = a11; bk1 = kbase + 32; }
        if (a12 > bv1) { bv1 = a12; bk1 = kbase + 64; }
        if (a13 > bv1) { bv1 = a13; bk1 = kbase + 96; }
    }

    rv[0][qp][kt2] = bv0; ri[0][qp][kt2] = bk0;
    rv[1][qp][kt2] = bv1; ri[1][qp][kt2] = bk1;
    __syncthreads();
    if (tid < QT2) {                 // one thread finalizes each row
        int half = tid >> 4, qq = tid & 15;
        float BV = -1.0f; int BKi = 1 << 30;
        for (int i = 0; i < 32; ++i) {
            float v = rv[half][qq][i];
            int  kk = ri[half][qq][i];
            if (v > BV || (v == BV && kk < BKi)) { BV = v; BKi = kk; }
        }
        idx_out[b * QLEN + q0 + half * 16 + qq] = (float)BKi;
    }
}

// =====================================================================
// Kernel 3: output projection  out = CTX @ Wo^T + bo
//   UNCHANGED from round 17 (full-reuse tiled GEMM, CTX in ws).
// =====================================================================
__global__ __launch_bounds__(256)
void oproj_gemm(const float* __restrict__ X, const float* __restrict__ W,
                const float* __restrict__ bias, float* __restrict__ Out)
{
    __shared__ float xs[GBM][GST];
    __shared__ float wsm[GBN][GST];

    const int m0 = blockIdx.y * GBM;
    const int n0 = blockIdx.x * GBN;
    const int tid = threadIdx.x;
    const int tx = tid & 15, ty = tid >> 4;

    float acc[4][4];
    #pragma unroll
    for (int i = 0; i < 4; ++i)
        #pragma unroll
        for (int j = 0; j < 4; ++j) acc[i][j] = 0.f;

    for (int k0 = 0; k0 < DIM; k0 += GBK) {
        #pragma unroll
        for (int p = 0; p < 2; ++p) {
            int f4 = tid + p * 256;
            int row = f4 >> 3;
            int c4 = (f4 & 7) << 2;
            *(float4*)&xs[row][c4]  = *(const float4*)&X[(size_t)(m0 + row) * DIM + k0 + c4];
            *(float4*)&wsm[row][c4] = *(const float4*)&W[(size_t)(n0 + row) * DIM + k0 + c4];
        }
        __syncthreads();
        #pragma unroll
        for (int kk = 0; kk < GBK; kk += 4) {
            float4 a4[4], b4[4];
            #pragma unroll
            for (int i = 0; i < 4; ++i) a4[i] = *(const float4*)&xs[ty + 16 * i][kk];
            #pragma unroll
            for (int j = 0; j < 4; ++j) b4[j] = *(const float4*)&wsm[tx + 16 * j][kk];
            #pragma unroll
            for (int i = 0; i < 4; ++i)
                #pragma unroll
                for (int j = 0; j < 4; ++j) {
                    acc[i][j] = fmaf(a4[i].x, b4[j].x, acc[i][j]);
                    acc[i][j] = fmaf(a4[i].y, b4[j].y, acc[i][j]);
                    acc[i][j] = fmaf(a4[i].z, b4[j].z, acc[i][j]);
                    acc[i][j] = fmaf(a4[i].w, b4[j].w, acc[i][j]);
                }
        }
        __syncthreads();
    }

    #pragma unroll
    for (int i = 0; i < 4; ++i) {
        int row = m0 + ty + 16 * i;
        #pragma unroll
        for (int j = 0; j < 4; ++j) {
            int col = n0 + tx + 16 * j;
            Out[(size_t)row * DIM + col] = acc[i][j] + bias[col];
        }
    }
}

// =====================================================================
extern "C" void kernel_launch(void* const* d_in, const int* in_sizes, int n_in,
                              void* d_out, int out_size, void* d_ws, size_t ws_size,
                              hipStream_t stream)
{
    (void)in_sizes; (void)n_in; (void)out_size; (void)ws_size;
    const float* query = (const float*)d_in[0];
    const int*   mask  = (const int*)  d_in[1];
    const float* Wq = (const float*)d_in[2];
    const float* bq = (const float*)d_in[3];
    const float* Wk = (const float*)d_in[4];
    const float* bk = (const float*)d_in[5];
    const float* Wv = (const float*)d_in[6];
    const float* bv = (const float*)d_in[7];
    const float* Wo = (const float*)d_in[8];
    const float* bo = (const float*)d_in[9];

    float* out = (float*)d_out;
    const size_t NTOK = (size_t)BS * QLEN;     // 8192
    const size_t QKV  = NTOK * DIM;
    const size_t MLSZ = NTOK * NH * 2;
    float* Qw  = (float*)d_ws;                 // ws: 3x32 MB + 1 MB + 32 MB = 129 MB
    float* Kw  = Qw + QKV;
    float* Vw  = Kw + QKV;
    float* ML  = Vw + QKV;                     // [NTOK][NH][2] f32
    float* CTX = ML + MLSZ;                    // [NTOK][DIM] f32

    dim3 gemm_grid3(DIM / GBN, (BS * QLEN) / GBM, 3);   // (16, 128, 3)
    qkv_gemm_fused<<<gemm_grid3, dim3(256), 0, stream>>>(
        query, Wq, bq, Qw, Wk, bk, Kw, Wv, bv, Vw);

    float* idx = out + NTOK * DIM;     // argmax output tail
    attn_kernel<<<dim3(QLEN / QT2, BS), dim3(512), 0, stream>>>(Qw, Kw, Vw, mask, CTX, ML);
    hsum_argmax_kernel<<<dim3(QLEN / QT2, BS), dim3(512), 0, stream>>>(Qw, Kw, mask, ML, idx);

    dim3 gemm_grid(DIM / GBN, (BS * QLEN) / GBM);       // (16, 128)
    oproj_gemm<<<gemm_grid, dim3(256), 0, stream>>>(CTX, Wo, bo, out);
}

// Round 20
// 3337.629 us; speedup vs baseline: 7.3184x; 1.0005x over previous
//
#include <hip/hip_runtime.h>
#include <math.h>

#define BS   4
#define QLEN 2048
#define DIM  1024
#define NH   16
#define DH   64

// =====================================================================
// Kernel 1: fused QKV projection GEMM (gridDim.z selects Q/K/V).
//   UNCHANGED from round 17.
// =====================================================================
#define GBM 64
#define GBN 64
#define GBK 32
#define GST (GBK + 4)    // 36 floats: 144B rows, 16B-aligned

__global__ __launch_bounds__(256)
void qkv_gemm_fused(const float* __restrict__ X,
                    const float* __restrict__ Wq, const float* __restrict__ bq, float* __restrict__ Oq,
                    const float* __restrict__ Wk, const float* __restrict__ bk, float* __restrict__ Ok,
                    const float* __restrict__ Wv, const float* __restrict__ bv, float* __restrict__ Ov)
{
    const float* W;  const float* bias;  float* Out;  float scale;
    if (blockIdx.z == 0)      { W = Wq; bias = bq; Out = Oq; scale = 0.125f; }
    else if (blockIdx.z == 1) { W = Wk; bias = bk; Out = Ok; scale = 1.0f;   }
    else                      { W = Wv; bias = bv; Out = Ov; scale = 1.0f;   }

    __shared__ float xs[GBM][GST];
    __shared__ float wsm[GBN][GST];

    const int m0 = blockIdx.y * GBM;
    const int n0 = blockIdx.x * GBN;
    const int tid = threadIdx.x;
    const int tx = tid & 15, ty = tid >> 4;

    float acc[4][4];
    #pragma unroll
    for (int i = 0; i < 4; ++i)
        #pragma unroll
        for (int j = 0; j < 4; ++j) acc[i][j] = 0.f;

    for (int k0 = 0; k0 < DIM; k0 += GBK) {
        #pragma unroll
        for (int p = 0; p < 2; ++p) {
            int f4 = tid + p * 256;
            int row = f4 >> 3;
            int c4 = (f4 & 7) << 2;
            *(float4*)&xs[row][c4]  = *(const float4*)&X[(size_t)(m0 + row) * DIM + k0 + c4];
            *(float4*)&wsm[row][c4] = *(const float4*)&W[(size_t)(n0 + row) * DIM + k0 + c4];
        }
        __syncthreads();
        #pragma unroll
        for (int kk = 0; kk < GBK; kk += 4) {
            float4 a4[4], b4[4];
            #pragma unroll
            for (int i = 0; i < 4; ++i) a4[i] = *(const float4*)&xs[ty + 16 * i][kk];
            #pragma unroll
            for (int j = 0; j < 4; ++j) b4[j] = *(const float4*)&wsm[tx + 16 * j][kk];
            #pragma unroll
            for (int i = 0; i < 4; ++i)
                #pragma unroll
                for (int j = 0; j < 4; ++j) {
                    acc[i][j] = fmaf(a4[i].x, b4[j].x, acc[i][j]);
                    acc[i][j] = fmaf(a4[i].y, b4[j].y, acc[i][j]);
                    acc[i][j] = fmaf(a4[i].z, b4[j].z, acc[i][j]);
                    acc[i][j] = fmaf(a4[i].w, b4[j].w, acc[i][j]);
                }
        }
        __syncthreads();
    }

    #pragma unroll
    for (int i = 0; i < 4; ++i) {
        int row = m0 + ty + 16 * i;
        int b_ = row >> 11;
        int s_ = row & 2047;
        #pragma unroll
        for (int j = 0; j < 4; ++j) {
            int col = n0 + tx + 16 * j;
            int h_ = col >> 6, d_ = col & 63;
            float v = (acc[i][j] + bias[col]) * scale;
            Out[((size_t)((b_ * NH + h_) * QLEN + s_)) * DH + d_] = v;
        }
    }
}

// =====================================================================
// Kernel 2: flash attention — REVERTED to the round-17 version (1.66 ms,
//   VGPR 96, zero conflicts). r18 lesson (3rd confirmation): any score-
//   phase restructure adding >=16 live registers spills at the 512-thread
//   128-VGPR ceiling (r8, r15, r18). The 2-row score phase is the
//   practical optimum for this block shape.
// =====================================================================
#define QT2 32
#define KC  128
#define NCH (QLEN / KC)   // 16

__device__ __forceinline__ void pv_row(const float4& wr,
                                       const float4& v0, const float4& v1,
                                       const float4& v2, const float4& v3,
                                       float& c0, float& c1, float& c2, float& c3)
{
    c0 = fmaf(wr.x, v0.x, c0); c1 = fmaf(wr.x, v0.y, c1);
    c2 = fmaf(wr.x, v0.z, c2); c3 = fmaf(wr.x, v0.w, c3);
    c0 = fmaf(wr.y, v1.x, c0); c1 = fmaf(wr.y, v1.y, c1);
    c2 = fmaf(wr.y, v1.z, c2); c3 = fmaf(wr.y, v1.w, c3);
    c0 = fmaf(wr.z, v2.x, c0); c1 = fmaf(wr.z, v2.y, c1);
    c2 = fmaf(wr.z, v2.z, c2); c3 = fmaf(wr.z, v2.w, c3);
    c0 = fmaf(wr.w, v3.x, c0); c1 = fmaf(wr.w, v3.y, c1);
    c2 = fmaf(wr.w, v3.z, c2); c3 = fmaf(wr.w, v3.w, c3);
}

__global__ __launch_bounds__(512, 1)
void attn_kernel(const float* __restrict__ Qm, const float* __restrict__ Km,
                 const float* __restrict__ Vm, const int* __restrict__ mask,
                 float* __restrict__ ctx_out, float* __restrict__ MLbuf)
{
    __shared__ float qs[QT2][DH + 4];                 //  8.5 KB
    __shared__ __align__(16) float ks[KC][DH + 4];    // 34 KB (reused as reduce scratch)
    __shared__ float vs[KC][DH];                      // 32 KB
    __shared__ float wch[QT2][132];                   // 16.9 KB
    __shared__ int   msk[KC];
    __shared__ float m_lds[QT2];
    __shared__ float l_lds[QT2];
    __shared__ float scl[QT2];

    const int b   = blockIdx.y;
    const int q0  = blockIdx.x * QT2;
    const int tid = threadIdx.x;
    const int qp  = tid >> 5;        // 0..15  (score-phase row pair base)
    const int kt2 = tid & 31;        // 0..31  (score-phase k lane)
    const int part = tid >> 7;       // 0..3   (PV k-partition)
    const int sub  = tid & 127;
    const int pr   = (sub >> 4) << 2;  // PV row base: 0,4,...,28
    const int pc4  = (sub & 15) << 2;  // PV col base

    #pragma unroll 1
    for (int h = 0; h < NH; ++h) {
        const float* Qh = Qm + (((size_t)b * NH + h) * QLEN + q0) * DH;
        const float* Kh = Km + ((size_t)b * NH + h) * QLEN * DH;
        const float* Vh = Vm + ((size_t)b * NH + h) * QLEN * DH;

        {   // stage q-tile 32x64 (already includes 1/sqrt(dh)); covered by c=0 barrier
            int row = tid >> 4, c4 = (tid & 15) << 2;
            *(float4*)&qs[row][c4] = *(const float4*)&Qh[(size_t)row * DH + c4];
        }
        if (tid < QT2) { m_lds[tid] = -INFINITY; l_lds[tid] = 0.0f; }

        float cvA0 = 0.f, cvA1 = 0.f, cvA2 = 0.f, cvA3 = 0.f;
        float cvB0 = 0.f, cvB1 = 0.f, cvB2 = 0.f, cvB3 = 0.f;
        float cvC0 = 0.f, cvC1 = 0.f, cvC2 = 0.f, cvC3 = 0.f;
        float cvD0 = 0.f, cvD1 = 0.f, cvD2 = 0.f, cvD3 = 0.f;

        #pragma unroll 1
        for (int c = 0; c < NCH; ++c) {
            #pragma unroll
            for (int p = 0; p < 4; ++p) {
                int f4 = tid + p * 512;
                int row = f4 >> 4, c4 = (f4 & 15) << 2;
                *(float4*)&ks[row][c4] = *(const float4*)&Kh[(size_t)(c * KC + row) * DH + c4];
                *(float4*)&vs[row][c4] = *(const float4*)&Vh[(size_t)(c * KC + row) * DH + c4];
            }
            if (tid < KC) msk[tid] = mask[b * QLEN + c * KC + tid];
            __syncthreads();

            // ---- scores: rows {qp, qp+16} x slots kt2+32jj, ascending-d chain ----
            float s0[4], s1[4];
            #pragma unroll
            for (int jj = 0; jj < 4; ++jj) { s0[jj] = 0.f; s1[jj] = 0.f; }
            #pragma unroll
            for (int d0 = 0; d0 < DH; d0 += 4) {
                float4 qv0 = *(const float4*)&qs[qp][d0];
                float4 qv1 = *(const float4*)&qs[qp + 16][d0];
                #pragma unroll
                for (int jj = 0; jj < 4; ++jj) {
                    float4 kv = *(const float4*)&ks[kt2 + 32 * jj][d0];
                    s0[jj] = fmaf(qv0.x, kv.x, s0[jj]);
                    s0[jj] = fmaf(qv0.y, kv.y, s0[jj]);
                    s0[jj] = fmaf(qv0.z, kv.z, s0[jj]);
                    s0[jj] = fmaf(qv0.w, kv.w, s0[jj]);
                    s1[jj] = fmaf(qv1.x, kv.x, s1[jj]);
                    s1[jj] = fmaf(qv1.y, kv.y, s1[jj]);
                    s1[jj] = fmaf(qv1.z, kv.z, s1[jj]);
                    s1[jj] = fmaf(qv1.w, kv.w, s1[jj]);
                }
            }
            float mm0 = -INFINITY, mm1 = -INFINITY;
            #pragma unroll
            for (int jj = 0; jj < 4; ++jj) {
                s0[jj] = msk[kt2 + 32 * jj] ? s0[jj] : -INFINITY;
                s1[jj] = msk[kt2 + 32 * jj] ? s1[jj] : -INFINITY;
                mm0 = fmaxf(mm0, s0[jj]);
                mm1 = fmaxf(mm1, s1[jj]);
            }
            #pragma unroll
            for (int off = 1; off < 32; off <<= 1) {
                mm0 = fmaxf(mm0, __shfl_xor(mm0, off, 64));
                mm1 = fmaxf(mm1, __shfl_xor(mm1, off, 64));
            }
            float mold0 = m_lds[qp], mold1 = m_lds[qp + 16];
            float mnew0 = fmaxf(mold0, mm0), mnew1 = fmaxf(mold1, mm1);
            float sc0 = (mnew0 > -INFINITY) ? __expf(mold0 - mnew0) : 0.0f;
            float sc1 = (mnew1 > -INFINITY) ? __expf(mold1 - mnew1) : 0.0f;
            float ls0 = 0.f, ls1 = 0.f;
            #pragma unroll
            for (int jj = 0; jj < 4; ++jj) {
                float w0 = (s0[jj] > -INFINITY) ? __expf(s0[jj] - mnew0) : 0.0f;
                float w1 = (s1[jj] > -INFINITY) ? __expf(s1[jj] - mnew1) : 0.0f;
                wch[qp][kt2 + 32 * jj]      = w0;
                wch[qp + 16][kt2 + 32 * jj] = w1;
                ls0 += w0;
                ls1 += w1;
            }
            #pragma unroll
            for (int off = 1; off < 32; off <<= 1) {
                ls0 += __shfl_xor(ls0, off, 64);
                ls1 += __shfl_xor(ls1, off, 64);
            }
            if (kt2 == 0) {
                l_lds[qp]      = l_lds[qp]      * sc0 + ls0;
                l_lds[qp + 16] = l_lds[qp + 16] * sc1 + ls1;
                m_lds[qp]      = mnew0;
                m_lds[qp + 16] = mnew1;
                scl[qp]        = sc0;
                scl[qp + 16]   = sc1;
            }
            __syncthreads();   // wch + scl ready

            // ---- PV: all 512 threads; 4x4 tile over k-partition `part` ----
            {
                float sA = scl[pr], sB = scl[pr + 1], sC = scl[pr + 2], sD = scl[pr + 3];
                cvA0 *= sA; cvA1 *= sA; cvA2 *= sA; cvA3 *= sA;
                cvB0 *= sB; cvB1 *= sB; cvB2 *= sB; cvB3 *= sB;
                cvC0 *= sC; cvC1 *= sC; cvC2 *= sC; cvC3 *= sC;
                cvD0 *= sD; cvD1 *= sD; cvD2 *= sD; cvD3 *= sD;
                const int kbase = part * 32;
                #pragma unroll 2
                for (int kk = 0; kk < 32; kk += 4) {
                    int k0 = kbase + kk;
                    float4 wA = *(const float4*)&wch[pr    ][k0];
                    float4 wB = *(const float4*)&wch[pr + 1][k0];
                    float4 wC = *(const float4*)&wch[pr + 2][k0];
                    float4 wD = *(const float4*)&wch[pr + 3][k0];
                    float4 v0 = *(const float4*)&vs[k0    ][pc4];
                    float4 v1 = *(const float4*)&vs[k0 + 1][pc4];
                    float4 v2 = *(const float4*)&vs[k0 + 2][pc4];
                    float4 v3 = *(const float4*)&vs[k0 + 3][pc4];
                    pv_row(wA, v0, v1, v2, v3, cvA0, cvA1, cvA2, cvA3);
                    pv_row(wB, v0, v1, v2, v3, cvB0, cvB1, cvB2, cvB3);
                    pv_row(wC, v0, v1, v2, v3, cvC0, cvC1, cvC2, cvC3);
                    pv_row(wD, v0, v1, v2, v3, cvD0, cvD1, cvD2, cvD3);
                }
            }
            __syncthreads();   // before next chunk overwrites ks/vs/wch
        }

        // ---- reduce the 4 k-partition partials (LDS scratch = ks region) ----
        float4* red4 = (float4*)&ks[0][0];
        if (part != 0) {
            int base = sub * 13 + (part - 1) * 4;
            red4[base + 0] = make_float4(cvA0, cvA1, cvA2, cvA3);
            red4[base + 1] = make_float4(cvB0, cvB1, cvB2, cvB3);
            red4[base + 2] = make_float4(cvC0, cvC1, cvC2, cvC3);
            red4[base + 3] = make_float4(cvD0, cvD1, cvD2, cvD3);
        }
        __syncthreads();
        if (part == 0) {
            #pragma unroll
            for (int p = 0; p < 3; ++p) {
                int base = sub * 13 + p * 4;
                float4 rA = red4[base + 0], rB = red4[base + 1];
                float4 rC = red4[base + 2], rD = red4[base + 3];
                cvA0 += rA.x; cvA1 += rA.y; cvA2 += rA.z; cvA3 += rA.w;
                cvB0 += rB.x; cvB1 += rB.y; cvB2 += rB.z; cvB3 += rB.w;
                cvC0 += rC.x; cvC1 += rC.y; cvC2 += rC.z; cvC3 += rC.w;
                cvD0 += rD.x; cvD1 += rD.y; cvD2 += rD.z; cvD3 += rD.w;
            }
            float LA = l_lds[pr], LB = l_lds[pr + 1], LC = l_lds[pr + 2], LD = l_lds[pr + 3];
            float* base = ctx_out + ((size_t)(b * QLEN + q0)) * DIM + h * DH + pc4;
            *(float4*)&base[(size_t)(pr    ) * DIM] = make_float4(cvA0 / LA, cvA1 / LA, cvA2 / LA, cvA3 / LA);
            *(float4*)&base[(size_t)(pr + 1) * DIM] = make_float4(cvB0 / LB, cvB1 / LB, cvB2 / LB, cvB3 / LB);
            *(float4*)&base[(size_t)(pr + 2) * DIM] = make_float4(cvC0 / LC, cvC1 / LC, cvC2 / LC, cvC3 / LC);
            *(float4*)&base[(size_t)(pr + 3) * DIM] = make_float4(cvD0 / LD, cvD1 / LD, cvD2 / LD, cvD3 / LD);
        }
        if (tid < QT2) {   // side-channel for the hsum/argmax kernel
            float* mlp = MLbuf + (((size_t)(b * QLEN + q0 + tid)) * NH + h) * 2;
            mlp[0] = m_lds[tid];
            mlp[1] = l_lds[tid];
        }
        __syncthreads();   // reduce-scratch/L/M reads done before next head
    }
}

// =====================================================================
// Kernel 2b: head-summed softmax weights -> argmax (QT2=32).
//   UNCHANGED from round 17 (__expf + staged reciprocal — validated).
// =====================================================================
__global__ __launch_bounds__(512, 4)
void hsum_argmax_kernel(const float* __restrict__ Qm, const float* __restrict__ Km,
                        const int* __restrict__ mask, const float* __restrict__ MLbuf,
                        float* __restrict__ idx_out)
{
    __shared__ float qs[QT2][DH + 4];    //  8.7 KB (restaged per h)
    __shared__ float ks[KC][DH + 4];     // 34 KB
    __shared__ float Mh[NH][QT2];        //  2 KB
    __shared__ float Lh[NH][QT2];        //  2 KB  (stores 1/L)
    __shared__ int   msk[KC];
    __shared__ float rv[2][16][32];      //  4 KB
    __shared__ int   ri[2][16][32];      //  4 KB

    const int b   = blockIdx.y;
    const int q0  = blockIdx.x * QT2;
    const int tid = threadIdx.x;
    const int qp  = tid >> 5;        // 0..15
    const int kt2 = tid & 31;        // 0..31

    {   // stage per-(row,h) softmax stats: 512 = 16h x 32rows
        int h = tid >> 5, rr = tid & 31;
        const float* mlp = MLbuf + (((size_t)(b * QLEN + q0 + rr)) * NH + h) * 2;
        Mh[h][rr] = mlp[0];
        Lh[h][rr] = 1.0f / mlp[1];
    }   // visibility covered by the first staging barrier below

    float bv0 = -1.0f, bv1 = -1.0f; int bk0 = 0, bk1 = 0;
    #pragma unroll 1
    for (int c = 0; c < NCH; ++c) {
        float a00 = 0.f, a01 = 0.f, a02 = 0.f, a03 = 0.f;   // row qp
        float a10 = 0.f, a11 = 0.f, a12 = 0.f, a13 = 0.f;   // row qp+16
        #pragma unroll 1
        for (int h = 0; h < NH; ++h) {
            __syncthreads();          // previous readers of ks/qs/msk done
            const float* Kh = Km + ((size_t)b * NH + h) * QLEN * DH;
            #pragma unroll
            for (int p = 0; p < 4; ++p) {
                int f4 = tid + p * 512;
                int row = f4 >> 4, c4 = (f4 & 15) << 2;
                *(float4*)&ks[row][c4] = *(const float4*)&Kh[(size_t)(c * KC + row) * DH + c4];
            }
            {   // stage q-tile 32x64 for head h
                const float* Qh = Qm + (((size_t)b * NH + h) * QLEN + q0) * DH;
                int row = tid >> 4, c4 = (tid & 15) << 2;
                *(float4*)&qs[row][c4] = *(const float4*)&Qh[(size_t)row * DH + c4];
            }
            if (h == 0 && tid < KC) msk[tid] = mask[b * QLEN + c * KC + tid];
            __syncthreads();

            float s0[4], s1[4];
            #pragma unroll
            for (int jj = 0; jj < 4; ++jj) { s0[jj] = 0.f; s1[jj] = 0.f; }
            #pragma unroll 4
            for (int d0 = 0; d0 < DH; d0 += 4) {
                float4 qv0 = *(const float4*)&qs[qp][d0];
                float4 qv1 = *(const float4*)&qs[qp + 16][d0];
                #pragma unroll
                for (int jj = 0; jj < 4; ++jj) {
                    float4 kv = *(const float4*)&ks[kt2 + 32 * jj][d0];
                    s0[jj] = fmaf(qv0.x, kv.x, s0[jj]);
                    s0[jj] = fmaf(qv0.y, kv.y, s0[jj]);
                    s0[jj] = fmaf(qv0.z, kv.z, s0[jj]);
                    s0[jj] = fmaf(qv0.w, kv.w, s0[jj]);
                    s1[jj] = fmaf(qv1.x, kv.x, s1[jj]);
                    s1[jj] = fmaf(qv1.y, kv.y, s1[jj]);
                    s1[jj] = fmaf(qv1.z, kv.z, s1[jj]);
                    s1[jj] = fmaf(qv1.w, kv.w, s1[jj]);
                }
            }
            const float Mv0 = Mh[h][qp],      rL0 = Lh[h][qp];
            const float Mv1 = Mh[h][qp + 16], rL1 = Lh[h][qp + 16];
            int mk0 = msk[kt2], mk1 = msk[kt2 + 32], mk2 = msk[kt2 + 64], mk3 = msk[kt2 + 96];
            a00 += mk0 ? __expf(s0[0] - Mv0) * rL0 : 0.f;
            a01 += mk1 ? __expf(s0[1] - Mv0) * rL0 : 0.f;
            a02 += mk2 ? __expf(s0[2] - Mv0) * rL0 : 0.f;
            a03 += mk3 ? __expf(s0[3] - Mv0) * rL0 : 0.f;
            a10 += mk0 ? __expf(s1[0] - Mv1) * rL1 : 0.f;
            a11 += mk1 ? __expf(s1[1] - Mv1) * rL1 : 0.f;
            a12 += mk2 ? __expf(s1[2] - Mv1) * rL1 : 0.f;
            a13 += mk3 ? __expf(s1[3] - Mv1) * rL1 : 0.f;
        }
        // k ascending across (c, jj) for fixed kt2 -> '>' keeps first index
        int kbase = c * KC + kt2;
        if (a00 > bv0) { bv0 = a00; bk0 = kbase;      }
        if (a01 > bv0) { bv0 = a01; bk0 = kbase + 32; }
        if (a02 > bv0) { bv0 = a02; bk0 = kbase + 64; }
        if (a03 > bv0) { bv0 = a03; bk0 = kbase + 96; }
        if (a10 > bv1) { bv1 = a10; bk1 = kbase;      }
        if (a11 > bv1) { bv1 = a11; bk1 = kbase + 32; }
        if (a12 > bv1) { bv1 = a12; bk1 = kbase + 64; }
        if (a13 > bv1) { bv1 = a13; bk1 = kbase + 96; }
    }

    rv[0][qp][kt2] = bv0; ri[0][qp][kt2] = bk0;
    rv[1][qp][kt2] = bv1; ri[1][qp][kt2] = bk1;
    __syncthreads();
    if (tid < QT2) {                 // one thread finalizes each row
        int half = tid >> 4, qq = tid & 15;
        float BV = -1.0f; int BKi = 1 << 30;
        for (int i = 0; i < 32; ++i) {
            float v = rv[half][qq][i];
            int  kk = ri[half][qq][i];
            if (v > BV || (v == BV && kk < BKi)) { BV = v; BKi = kk; }
        }
        idx_out[b * QLEN + q0 + half * 16 + qq] = (float)BKi;
    }
}

// =====================================================================
// Kernel 3: output projection  out = CTX @ Wo^T + bo
//   UNCHANGED from round 17 (full-reuse tiled GEMM, CTX in ws).
// =====================================================================
__global__ __launch_bounds__(256)
void oproj_gemm(const float* __restrict__ X, const float* __restrict__ W,
                const float* __restrict__ bias, float* __restrict__ Out)
{
    __shared__ float xs[GBM][GST];
    __shared__ float wsm[GBN][GST];

    const int m0 = blockIdx.y * GBM;
    const int n0 = blockIdx.x * GBN;
    const int tid = threadIdx.x;
    const int tx = tid & 15, ty = tid >> 4;

    float acc[4][4];
    #pragma unroll
    for (int i = 0; i < 4; ++i)
        #pragma unroll
        for (int j = 0; j < 4; ++j) acc[i][j] = 0.f;

    for (int k0 = 0; k0 < DIM; k0 += GBK) {
        #pragma unroll
        for (int p = 0; p < 2; ++p) {
            int f4 = tid + p * 256;
            int row = f4 >> 3;
            int c4 = (f4 & 7) << 2;
            *(float4*)&xs[row][c4]  = *(const float4*)&X[(size_t)(m0 + row) * DIM + k0 + c4];
            *(float4*)&wsm[row][c4] = *(const float4*)&W[(size_t)(n0 + row) * DIM + k0 + c4];
        }
        __syncthreads();
        #pragma unroll
        for (int kk = 0; kk < GBK; kk += 4) {
            float4 a4[4], b4[4];
            #pragma unroll
            for (int i = 0; i < 4; ++i) a4[i] = *(const float4*)&xs[ty + 16 * i][kk];
            #pragma unroll
            for (int j = 0; j < 4; ++j) b4[j] = *(const float4*)&wsm[tx + 16 * j][kk];
            #pragma unroll
            for (int i = 0; i < 4; ++i)
                #pragma unroll
                for (int j = 0; j < 4; ++j) {
                    acc[i][j] = fmaf(a4[i].x, b4[j].x, acc[i][j]);
                    acc[i][j] = fmaf(a4[i].y, b4[j].y, acc[i][j]);
                    acc[i][j] = fmaf(a4[i].z, b4[j].z, acc[i][j]);
                    acc[i][j] = fmaf(a4[i].w, b4[j].w, acc[i][j]);
                }
        }
        __syncthreads();
    }

    #pragma unroll
    for (int i = 0; i < 4; ++i) {
        int row = m0 + ty + 16 * i;
        #pragma unroll
        for (int j = 0; j < 4; ++j) {
            int col = n0 + tx + 16 * j;
            Out[(size_t)row * DIM + col] = acc[i][j] + bias[col];
        }
    }
}

// =====================================================================
extern "C" void kernel_launch(void* const* d_in, const int* in_sizes, int n_in,
                              void* d_out, int out_size, void* d_ws, size_t ws_size,
                              hipStream_t stream)
{
    (void)in_sizes; (void)n_in; (void)out_size; (void)ws_size;
    const float* query = (const float*)d_in[0];
    const int*   mask  = (const int*)  d_in[1];
    const float* Wq = (const float*)d_in[2];
    const float* bq = (const float*)d_in[3];
    const float* Wk = (const float*)d_in[4];
    const float* bk = (const float*)d_in[5];
    const float* Wv = (const float*)d_in[6];
    const float* bv = (const float*)d_in[7];
    const float* Wo = (const float*)d_in[8];
    const float* bo = (const float*)d_in[9];

    float* out = (float*)d_out;
    const size_t NTOK = (size_t)BS * QLEN;     // 8192
    const size_t QKV  = NTOK * DIM;
    const size_t MLSZ = NTOK * NH * 2;
    float* Qw  = (float*)d_ws;                 // ws: 3x32 MB + 1 MB + 32 MB = 129 MB
    float* Kw  = Qw + QKV;
    float* Vw  = Kw + QKV;
    float* ML  = Vw + QKV;                     // [NTOK][NH][2] f32
    float* CTX = ML + MLSZ;                    // [NTOK][DIM] f32

    dim3 gemm_grid3(DIM / GBN, (BS * QLEN) / GBM, 3);   // (16, 128, 3)
    qkv_gemm_fused<<<gemm_grid3, dim3(256), 0, stream>>>(
        query, Wq, bq, Qw, Wk, bk, Kw, Wv, bv, Vw);

    float* idx = out + NTOK * DIM;     // argmax output tail
    attn_kernel<<<dim3(QLEN / QT2, BS), dim3(512), 0, stream>>>(Qw, Kw, Vw, mask, CTX, ML);
    hsum_argmax_kernel<<<dim3(QLEN / QT2, BS), dim3(512), 0, stream>>>(Qw, Kw, mask, ML, idx);

    dim3 gemm_grid(DIM / GBN, (BS * QLEN) / GBM);       // (16, 128)
    oproj_gemm<<<gemm_grid, dim3(256), 0, stream>>>(CTX, Wo, bo, out);
}